// Round 12
// baseline (151.831 us; speedup 1.0000x reference)
//
#include <hip/hip_runtime.h>

// Point-transformer block. R11 = R10 (wave-autonomous groups, zero
// __syncthreads, SGPR weights, L2E-folded) but phase 2 processes all
// FOUR pairs per lane in ONE fused pass: 12 independent dot2 chains,
// 4-way shared aj/weight operands -> 2x ILP at ~equal instruction count.
// Discriminates latency-bound vs issue-bound.

typedef _Float16 h2 __attribute__((ext_vector_type(2)));
typedef _Float16 h8 __attribute__((ext_vector_type(8)));

#define AH_STRIDE 36   // a-table row stride in dwords (32 data + 4 pad)

union H8U { h8 v; h2 p[4]; unsigned u[4]; };

__device__ __forceinline__ h2 pkrtz(float a, float b) {
    return __builtin_bit_cast(h2, __builtin_amdgcn_cvt_pkrtz(a, b));
}
__device__ __forceinline__ h2 uash2(unsigned u) {
    return __builtin_bit_cast(h2, u);
}
__device__ __forceinline__ h2 hmax2(h2 a, h2 b) {
    return __builtin_elementwise_max(a, b);   // v_pk_max_f16
}

#if __has_builtin(__builtin_amdgcn_fdot2)
__device__ __forceinline__ float dot2acc(h2 a, h2 b, float c) {
    return __builtin_amdgcn_fdot2(a, b, c, false);
}
#else
__device__ __forceinline__ float dot2acc(h2 a, h2 b, float c) {
    float d;
    asm("v_dot2_f32_f16 %0, %1, %2, %3"
        : "=v"(d)
        : "v"(__builtin_bit_cast(int, a)), "v"(__builtin_bit_cast(int, b)), "v"(c));
    return d;
}
#endif

// sum across the 16-lane DPP row via row_ror 1,2,4,8 (all lanes get total)
__device__ __forceinline__ float dpp_add16(float x) {
    float s = x;
    int t;
    t = __builtin_amdgcn_update_dpp(0, __builtin_bit_cast(int, s), 0x121, 0xf, 0xf, false);
    s += __builtin_bit_cast(float, t);
    t = __builtin_amdgcn_update_dpp(0, __builtin_bit_cast(int, s), 0x122, 0xf, 0xf, false);
    s += __builtin_bit_cast(float, t);
    t = __builtin_amdgcn_update_dpp(0, __builtin_bit_cast(int, s), 0x124, 0xf, 0xf, false);
    s += __builtin_bit_cast(float, t);
    t = __builtin_amdgcn_update_dpp(0, __builtin_bit_cast(int, s), 0x128, 0xf, 0xf, false);
    s += __builtin_bit_cast(float, t);
    return s;
}

// ---- pre-kernel: pack f16-pair weight tables (aw2 pre-scaled by L2E) ----
__global__ void wpack(const float* __restrict__ pw2, const float* __restrict__ aw1,
                      const float* __restrict__ ab1, const float* __restrict__ aw2,
                      unsigned* __restrict__ ws) {
    const int t = threadIdx.x;
    const float L2E = 1.44269504f;
    if (t < 96) {
        const int hp = t & 31, c = t >> 5;
        ws[c*32+hp] = __builtin_bit_cast(unsigned, pkrtz(pw2[(2*hp)*3+c], pw2[(2*hp+1)*3+c]));
    } else if (t < 114) {
        const int idx = t - 96, r = idx / 6, gp = idx % 6;
        ws[96+r*6+gp] = __builtin_bit_cast(unsigned, pkrtz(aw1[r*12+2*gp], aw1[r*12+2*gp+1]));
    } else if (t < 120) {
        const int gp = t - 114;
        ws[114+gp] = __builtin_bit_cast(unsigned, pkrtz(ab1[2*gp], ab1[2*gp+1]));
    } else if (t < 138) {
        const int idx = t - 120, gp = idx / 3, c = idx % 3;
        ws[120+gp*3+c] = __builtin_bit_cast(unsigned,
            pkrtz(aw2[(2*gp)*3+c] * L2E, aw2[(2*gp+1)*3+c] * L2E));
    }
}

__global__ __launch_bounds__(256) void pt_main(
    const float* __restrict__ data,     // (BG, 16, 3)
    const float* __restrict__ wqkv,     // (3, 9)
    const float* __restrict__ pw1,      // (3, 64)
    const float* __restrict__ pb1,      // (64)
    const float* __restrict__ pb2,      // (3)
    const float* __restrict__ ab2,      // (3)
    const float* __restrict__ mw1,      // (48, 48)
    const float* __restrict__ mb1,      // (48)
    const float* __restrict__ mw2,      // (48, 48)
    const float* __restrict__ mb2,      // (48)
    const float* __restrict__ mw3,      // (48, 1)
    const float* __restrict__ mb3,      // (1)
    const unsigned* __restrict__ wsp,   // packed f16-pair weights (uniform)
    float* __restrict__ out)            // (BG)
{
    // all LDS sliced per wave — no cross-wave sharing, no __syncthreads
    __shared__ __attribute__((aligned(16))) float s_q4[4][64], s_k4[4][64], s_v4[4][64];
    __shared__ __attribute__((aligned(16))) float s_sa[4][48];
    __shared__ __attribute__((aligned(16))) float s_h1[4][48];
    __shared__ __attribute__((aligned(16))) unsigned s_a1h[4][16 * AH_STRIDE];
    __shared__ __attribute__((aligned(16))) unsigned s_a2h[4][16 * AH_STRIDE];

    const int t  = threadIdx.x;
    const int wv = t >> 6;
    const int ln = t & 63;
    const int g  = blockIdx.x * 4 + wv;

    // ---- phase 1a: qkv (lanes 0..47), stride-4 layout ----
    if (ln < 48) {
        const int sec = ln >> 4, p = ln & 15;
        const float x0 = data[g*48 + p*3 + 0];
        const float x1 = data[g*48 + p*3 + 1];
        const float x2 = data[g*48 + p*3 + 2];
        float* dst = (sec == 0) ? s_q4[wv] : (sec == 1) ? s_k4[wv] : s_v4[wv];
        #pragma unroll
        for (int c = 0; c < 3; ++c) {
            dst[p*4+c] = fmaf(x0, wqkv[0*9 + sec*3 + c],
                         fmaf(x1, wqkv[1*9 + sec*3 + c],
                         x2 * wqkv[2*9 + sec*3 + c]));
        }
        dst[p*4+3] = 0.0f;
    }

    // ---- phase 1b: a-tables. lane -> point p=ln&15, 16 hiddens at (ln>>4)*16 ----
    {
        const int p  = ln & 15;
        const int qd = ln >> 4;
        const int hc = qd << 4;
        const float x0 = data[g*48 + p*3 + 0];
        const float x1 = data[g*48 + p*3 + 1];
        const float x2 = data[g*48 + p*3 + 2];
        float s[16];
        #pragma unroll
        for (int c = 0; c < 16; ++c) {
            const int h = hc + c;
            s[c] = fmaf(x0, pw1[h], fmaf(x1, pw1[64+h], x2 * pw1[128+h]));
        }
        uint4 a1u0, a1u1, a2u0, a2u1;
        #pragma unroll
        for (int d = 0; d < 4; ++d) {
            const int c = d * 2;
            (&a1u0.x)[d] = __builtin_bit_cast(unsigned, pkrtz(s[c]   + pb1[hc+c],   s[c+1] + pb1[hc+c+1]));
            (&a1u1.x)[d] = __builtin_bit_cast(unsigned, pkrtz(s[8+c] + pb1[hc+8+c], s[9+c] + pb1[hc+9+c]));
            (&a2u0.x)[d] = __builtin_bit_cast(unsigned, pkrtz(s[c],   s[c+1]));
            (&a2u1.x)[d] = __builtin_bit_cast(unsigned, pkrtz(s[8+c], s[9+c]));
        }
        const int base = p * AH_STRIDE + (qd << 3);
        *(uint4*)&s_a1h[wv][base]     = a1u0;
        *(uint4*)&s_a1h[wv][base + 4] = a1u1;
        *(uint4*)&s_a2h[wv][base]     = a2u0;
        *(uint4*)&s_a2h[wv][base + 4] = a2u1;
    }
    __builtin_amdgcn_wave_barrier();   // order DS writes before phase-2 reads

    // ---- phase 2: ALL FOUR pairs per lane fused. j=ln&15, i in {q,q+4,q+8,q+12} ----
    const int j = ln & 15, q = ln >> 4;
    const float4 kv = *(const float4*)&s_k4[wv][j*4];
    const float4 vv = *(const float4*)&s_v4[wv][j*4];
    const h2 z2 = {(_Float16)0, (_Float16)0};
    const float L2E = 1.44269504f;
    const float mb_0 = ab2[0] * L2E, mb_1 = ab2[1] * L2E, mb_2 = ab2[2] * L2E;

    // hoist the j-side a-table (shared by all 4 pairs): 8 x b128
    H8U ajr[8];
    #pragma unroll
    for (int cc = 0; cc < 8; ++cc)
        ajr[cc].v = *(const h8*)&s_a2h[wv][j * AH_STRIDE + cc*4];

    // pos-MLP: 12 independent dot2 accumulator chains
    float e[4][3];
    #pragma unroll
    for (int pp = 0; pp < 4; ++pp) {
        e[pp][0] = pb2[0]; e[pp][1] = pb2[1]; e[pp][2] = pb2[2];
    }
    #pragma unroll
    for (int cc = 0; cc < 8; ++cc) {
        H8U ai[4];
        #pragma unroll
        for (int pp = 0; pp < 4; ++pp)
            ai[pp].v = *(const h8*)&s_a1h[wv][(q + 4*pp) * AH_STRIDE + cc*4];
        #pragma unroll
        for (int m = 0; m < 4; ++m) {
            const int hp = cc*4 + m;
            const h2 w0 = uash2(wsp[0*32+hp]);
            const h2 w1 = uash2(wsp[1*32+hp]);
            const h2 w2 = uash2(wsp[2*32+hp]);
            #pragma unroll
            for (int pp = 0; pp < 4; ++pp) {
                const h2 r = hmax2(ai[pp].p[m] - ajr[cc].p[m], z2);
                e[pp][0] = dot2acc(r, w0, e[pp][0]);
                e[pp][1] = dot2acc(r, w1, e[pp][1]);
                e[pp][2] = dot2acc(r, w2, e[pp][2]);
            }
        }
    }

    // si / vi for all 4 pairs
    float vi[4][3], mAcc[4][3];
    h2 sp[4][3];
    #pragma unroll
    for (int pp = 0; pp < 4; ++pp) {
        const int ii = q + 4*pp;
        const float4 qv = *(const float4*)&s_q4[wv][ii*4];
        vi[pp][0] = vv.x + e[pp][0];
        vi[pp][1] = vv.y + e[pp][1];
        vi[pp][2] = vv.z + e[pp][2];
        const float s0 = qv.x - kv.x + e[pp][0];
        const float s1 = qv.y - kv.y + e[pp][1];
        const float s2 = qv.z - kv.z + e[pp][2];
        sp[pp][0] = pkrtz(s0, s0);
        sp[pp][1] = pkrtz(s1, s1);
        sp[pp][2] = pkrtz(s2, s2);
        mAcc[pp][0] = mb_0; mAcc[pp][1] = mb_1; mAcc[pp][2] = mb_2;
    }

    // attn-MLP in packed f16, 4 pairs interleaved (aw2/ab2 pre-scaled by L2E)
    #pragma unroll
    for (int gp = 0; gp < 6; ++gp) {
        const h2 b1p = uash2(wsp[114+gp]);
        const h2 u0 = uash2(wsp[96+0*6+gp]);
        const h2 u1 = uash2(wsp[96+1*6+gp]);
        const h2 u2 = uash2(wsp[96+2*6+gp]);
        const h2 v0 = uash2(wsp[120+gp*3+0]);
        const h2 v1 = uash2(wsp[120+gp*3+1]);
        const h2 v2 = uash2(wsp[120+gp*3+2]);
        #pragma unroll
        for (int pp = 0; pp < 4; ++pp) {
            h2 acc = b1p;
            acc = __builtin_elementwise_fma(sp[pp][0], u0, acc);
            acc = __builtin_elementwise_fma(sp[pp][1], u1, acc);
            acc = __builtin_elementwise_fma(sp[pp][2], u2, acc);
            const h2 hg = hmax2(acc, z2);
            mAcc[pp][0] = dot2acc(hg, v0, mAcc[pp][0]);
            mAcc[pp][1] = dot2acc(hg, v1, mAcc[pp][1]);
            mAcc[pp][2] = dot2acc(hg, v2, mAcc[pp][2]);
        }
    }

    // softmax over j (DPP row sums; exponents already in log2 domain)
    #pragma unroll
    for (int pp = 0; pp < 4; ++pp) {
        const float p0 = __builtin_amdgcn_exp2f(mAcc[pp][0]);
        const float p1 = __builtin_amdgcn_exp2f(mAcc[pp][1]);
        const float p2 = __builtin_amdgcn_exp2f(mAcc[pp][2]);
        const float n0 = dpp_add16(p0 * vi[pp][0]);
        const float n1 = dpp_add16(p1 * vi[pp][1]);
        const float n2 = dpp_add16(p2 * vi[pp][2]);
        const float d0 = dpp_add16(p0);
        const float d1 = dpp_add16(p1);
        const float d2 = dpp_add16(p2);
        if (j == 0) {
            const int ii = q + 4*pp;
            s_sa[wv][ii*3+0] = n0 * __builtin_amdgcn_rcpf(d0);
            s_sa[wv][ii*3+1] = n1 * __builtin_amdgcn_rcpf(d1);
            s_sa[wv][ii*3+2] = n2 * __builtin_amdgcn_rcpf(d2);
        }
    }
    __builtin_amdgcn_wave_barrier();   // s_sa writes before tail reads

    // ---- phase 3: MLP 48->48->48->1, per-wave (every wave = one group) ----
    if (ln < 48) {
        const int o = ln;
        float a0 = 0.f, a1 = 0.f, a2 = 0.f, a3 = 0.f;
        #pragma unroll
        for (int c = 0; c < 48; c += 4) {
            const float4 sa = *(const float4*)&s_sa[wv][c];   // broadcast read
            a0 = fmaf(sa.x, mw1[(c+0)*48+o], a0);
            a1 = fmaf(sa.y, mw1[(c+1)*48+o], a1);
            a2 = fmaf(sa.z, mw1[(c+2)*48+o], a2);
            a3 = fmaf(sa.w, mw1[(c+3)*48+o], a3);
        }
        s_h1[wv][o] = fmaxf((a0+a1) + (a2+a3) + mb1[o], 0.0f);
        __builtin_amdgcn_wave_barrier();   // same-wave LDS handoff
        float b0 = 0.f, b1 = 0.f, b2 = 0.f, b3 = 0.f;
        #pragma unroll
        for (int c = 0; c < 48; c += 4) {
            const float4 hh = *(const float4*)&s_h1[wv][c];
            b0 = fmaf(hh.x, mw2[(c+0)*48+o], b0);
            b1 = fmaf(hh.y, mw2[(c+1)*48+o], b1);
            b2 = fmaf(hh.z, mw2[(c+2)*48+o], b2);
            b3 = fmaf(hh.w, mw2[(c+3)*48+o], b3);
        }
        const float h2v = fmaxf((b0+b1) + (b2+b3) + mb2[o], 0.0f);
        const float fv = h2v * mw3[o];
        const float r = dpp_add16(fv);     // row sums in lanes 0,16,32
        const int ri = __builtin_bit_cast(int, r);
        const float tot =
            __builtin_bit_cast(float, __builtin_amdgcn_readlane(ri, 0)) +
            __builtin_bit_cast(float, __builtin_amdgcn_readlane(ri, 16)) +
            __builtin_bit_cast(float, __builtin_amdgcn_readlane(ri, 32));
        if (o == 0) out[g] = tot + mb3[0];
    }
}

extern "C" void kernel_launch(void* const* d_in, const int* in_sizes, int n_in,
                              void* d_out, int out_size, void* d_ws, size_t ws_size,
                              hipStream_t stream) {
    const float* data = (const float*)d_in[1];
    unsigned* ws = (unsigned*)d_ws;
    const int groups = out_size;  // B*G = 16384

    wpack<<<1, 256, 0, stream>>>(
        (const float*)d_in[5],   // pw2
        (const float*)d_in[7],   // aw1
        (const float*)d_in[8],   // ab1
        (const float*)d_in[9],   // aw2
        ws);

    pt_main<<<groups / 4, 256, 0, stream>>>(
        data,
        (const float*)d_in[2],   // wqkv
        (const float*)d_in[3],   // pw1
        (const float*)d_in[4],   // pb1
        (const float*)d_in[6],   // pb2
        (const float*)d_in[10],  // ab2
        (const float*)d_in[11],  // mw1
        (const float*)d_in[12],  // mb1
        (const float*)d_in[13],  // mw2
        (const float*)d_in[14],  // mb2
        (const float*)d_in[15],  // mw3
        (const float*)d_in[16],  // mb3
        ws,
        (float*)d_out);
}

// Round 13
// 137.945 us; speedup vs baseline: 1.1007x; 1.1007x over previous
//
#include <hip/hip_runtime.h>

// Point-transformer block. R12 = R10 structure (best: wave-autonomous
// group, 2+2 pair halves, SGPR weights, L2E folded, zero __syncthreads)
// but ONE WAVE PER BLOCK: 64 threads, grid = groups. LDS 5.8 KB/block
// -> ~27 blocks/CU static limit; finer dispatch granularity.

typedef _Float16 h2 __attribute__((ext_vector_type(2)));
typedef _Float16 h8 __attribute__((ext_vector_type(8)));

#define AH_STRIDE 36   // a-table row stride in dwords (32 data + 4 pad)

union H8U { h8 v; h2 p[4]; unsigned u[4]; };

__device__ __forceinline__ h2 pkrtz(float a, float b) {
    return __builtin_bit_cast(h2, __builtin_amdgcn_cvt_pkrtz(a, b));
}
__device__ __forceinline__ h2 uash2(unsigned u) {
    return __builtin_bit_cast(h2, u);
}
__device__ __forceinline__ h2 hmax2(h2 a, h2 b) {
    return __builtin_elementwise_max(a, b);   // v_pk_max_f16
}

#if __has_builtin(__builtin_amdgcn_fdot2)
__device__ __forceinline__ float dot2acc(h2 a, h2 b, float c) {
    return __builtin_amdgcn_fdot2(a, b, c, false);
}
#else
__device__ __forceinline__ float dot2acc(h2 a, h2 b, float c) {
    float d;
    asm("v_dot2_f32_f16 %0, %1, %2, %3"
        : "=v"(d)
        : "v"(__builtin_bit_cast(int, a)), "v"(__builtin_bit_cast(int, b)), "v"(c));
    return d;
}
#endif

// sum across the 16-lane DPP row via row_ror 1,2,4,8 (all lanes get total)
__device__ __forceinline__ float dpp_add16(float x) {
    float s = x;
    int t;
    t = __builtin_amdgcn_update_dpp(0, __builtin_bit_cast(int, s), 0x121, 0xf, 0xf, false);
    s += __builtin_bit_cast(float, t);
    t = __builtin_amdgcn_update_dpp(0, __builtin_bit_cast(int, s), 0x122, 0xf, 0xf, false);
    s += __builtin_bit_cast(float, t);
    t = __builtin_amdgcn_update_dpp(0, __builtin_bit_cast(int, s), 0x124, 0xf, 0xf, false);
    s += __builtin_bit_cast(float, t);
    t = __builtin_amdgcn_update_dpp(0, __builtin_bit_cast(int, s), 0x128, 0xf, 0xf, false);
    s += __builtin_bit_cast(float, t);
    return s;
}

// ---- pre-kernel: pack f16-pair weight tables (aw2 pre-scaled by L2E) ----
__global__ void wpack(const float* __restrict__ pw2, const float* __restrict__ aw1,
                      const float* __restrict__ ab1, const float* __restrict__ aw2,
                      unsigned* __restrict__ ws) {
    const int t = threadIdx.x;
    const float L2E = 1.44269504f;
    if (t < 96) {
        const int hp = t & 31, c = t >> 5;
        ws[c*32+hp] = __builtin_bit_cast(unsigned, pkrtz(pw2[(2*hp)*3+c], pw2[(2*hp+1)*3+c]));
    } else if (t < 114) {
        const int idx = t - 96, r = idx / 6, gp = idx % 6;
        ws[96+r*6+gp] = __builtin_bit_cast(unsigned, pkrtz(aw1[r*12+2*gp], aw1[r*12+2*gp+1]));
    } else if (t < 120) {
        const int gp = t - 114;
        ws[114+gp] = __builtin_bit_cast(unsigned, pkrtz(ab1[2*gp], ab1[2*gp+1]));
    } else if (t < 138) {
        const int idx = t - 120, gp = idx / 3, c = idx % 3;
        ws[120+gp*3+c] = __builtin_bit_cast(unsigned,
            pkrtz(aw2[(2*gp)*3+c] * L2E, aw2[(2*gp+1)*3+c] * L2E));
    }
}

__global__ __launch_bounds__(64, 8) void pt_main(
    const float* __restrict__ data,     // (BG, 16, 3)
    const float* __restrict__ wqkv,     // (3, 9)
    const float* __restrict__ pw1,      // (3, 64)
    const float* __restrict__ pb1,      // (64)
    const float* __restrict__ pb2,      // (3)
    const float* __restrict__ ab2,      // (3)
    const float* __restrict__ mw1,      // (48, 48)
    const float* __restrict__ mb1,      // (48)
    const float* __restrict__ mw2,      // (48, 48)
    const float* __restrict__ mb2,      // (48)
    const float* __restrict__ mw3,      // (48, 1)
    const float* __restrict__ mb3,      // (1)
    const unsigned* __restrict__ wsp,   // packed f16-pair weights (uniform)
    float* __restrict__ out)            // (BG)
{
    __shared__ __attribute__((aligned(16))) float s_q4[64], s_k4[64], s_v4[64];
    __shared__ __attribute__((aligned(16))) float s_sa[48];
    __shared__ __attribute__((aligned(16))) float s_h1[48];
    __shared__ __attribute__((aligned(16))) unsigned s_a1h[16 * AH_STRIDE];
    __shared__ __attribute__((aligned(16))) unsigned s_a2h[16 * AH_STRIDE];

    const int ln = threadIdx.x;
    const int g  = blockIdx.x;

    // ---- phase 1a: qkv (lanes 0..47), stride-4 layout ----
    if (ln < 48) {
        const int sec = ln >> 4, p = ln & 15;
        const float x0 = data[g*48 + p*3 + 0];
        const float x1 = data[g*48 + p*3 + 1];
        const float x2 = data[g*48 + p*3 + 2];
        float* dst = (sec == 0) ? s_q4 : (sec == 1) ? s_k4 : s_v4;
        #pragma unroll
        for (int c = 0; c < 3; ++c) {
            dst[p*4+c] = fmaf(x0, wqkv[0*9 + sec*3 + c],
                         fmaf(x1, wqkv[1*9 + sec*3 + c],
                         x2 * wqkv[2*9 + sec*3 + c]));
        }
        dst[p*4+3] = 0.0f;
    }

    // ---- phase 1b: a-tables. lane -> point p=ln&15, 16 hiddens at (ln>>4)*16 ----
    {
        const int p  = ln & 15;
        const int qd = ln >> 4;
        const int hc = qd << 4;
        const float x0 = data[g*48 + p*3 + 0];
        const float x1 = data[g*48 + p*3 + 1];
        const float x2 = data[g*48 + p*3 + 2];
        float s[16];
        #pragma unroll
        for (int c = 0; c < 16; ++c) {
            const int h = hc + c;
            s[c] = fmaf(x0, pw1[h], fmaf(x1, pw1[64+h], x2 * pw1[128+h]));
        }
        uint4 a1u0, a1u1, a2u0, a2u1;
        #pragma unroll
        for (int d = 0; d < 4; ++d) {
            const int c = d * 2;
            (&a1u0.x)[d] = __builtin_bit_cast(unsigned, pkrtz(s[c]   + pb1[hc+c],   s[c+1] + pb1[hc+c+1]));
            (&a1u1.x)[d] = __builtin_bit_cast(unsigned, pkrtz(s[8+c] + pb1[hc+8+c], s[9+c] + pb1[hc+9+c]));
            (&a2u0.x)[d] = __builtin_bit_cast(unsigned, pkrtz(s[c],   s[c+1]));
            (&a2u1.x)[d] = __builtin_bit_cast(unsigned, pkrtz(s[8+c], s[9+c]));
        }
        const int base = p * AH_STRIDE + (qd << 3);
        *(uint4*)&s_a1h[base]     = a1u0;
        *(uint4*)&s_a1h[base + 4] = a1u1;
        *(uint4*)&s_a2h[base]     = a2u0;
        *(uint4*)&s_a2h[base + 4] = a2u1;
    }
    __builtin_amdgcn_wave_barrier();   // order DS writes before phase-2 reads

    // ---- phase 2: 4 pairs per lane, processed 2+2. j=ln&15, i in {q,q+4,q+8,q+12} ----
    const int j = ln & 15, q = ln >> 4;
    const float4 kv = *(const float4*)&s_k4[j*4];
    const float4 vv = *(const float4*)&s_v4[j*4];
    const h2 z2 = {(_Float16)0, (_Float16)0};
    const float L2E = 1.44269504f;
    const float mb_0 = ab2[0] * L2E, mb_1 = ab2[1] * L2E, mb_2 = ab2[2] * L2E;

    // hoist the j-side a-table (shared by all 4 pairs): 8 x b128
    H8U ajr[8];
    #pragma unroll
    for (int cc = 0; cc < 8; ++cc)
        ajr[cc].v = *(const h8*)&s_a2h[j * AH_STRIDE + cc*4];

    #pragma unroll
    for (int half = 0; half < 2; ++half) {
        const int iA = q + 8*half, iB = iA + 4;

        float eA0 = pb2[0], eA1 = pb2[1], eA2 = pb2[2];
        float eB0 = pb2[0], eB1 = pb2[1], eB2 = pb2[2];
        #pragma unroll
        for (int cc = 0; cc < 8; ++cc) {
            H8U aiA, aiB;
            aiA.v = *(const h8*)&s_a1h[iA * AH_STRIDE + cc*4];
            aiB.v = *(const h8*)&s_a1h[iB * AH_STRIDE + cc*4];
            #pragma unroll
            for (int m = 0; m < 4; ++m) {
                const int hp = cc*4 + m;
                const h2 w0 = uash2(wsp[0*32+hp]);
                const h2 w1 = uash2(wsp[1*32+hp]);
                const h2 w2 = uash2(wsp[2*32+hp]);
                h2 rA = hmax2(aiA.p[m] - ajr[cc].p[m], z2);
                h2 rB = hmax2(aiB.p[m] - ajr[cc].p[m], z2);
                eA0 = dot2acc(rA, w0, eA0);
                eA1 = dot2acc(rA, w1, eA1);
                eA2 = dot2acc(rA, w2, eA2);
                eB0 = dot2acc(rB, w0, eB0);
                eB1 = dot2acc(rB, w1, eB1);
                eB2 = dot2acc(rB, w2, eB2);
            }
        }

        const float4 qA = *(const float4*)&s_q4[iA*4];
        const float4 qB = *(const float4*)&s_q4[iB*4];

        const float viA0 = vv.x + eA0, viA1 = vv.y + eA1, viA2 = vv.z + eA2;
        const float viB0 = vv.x + eB0, viB1 = vv.y + eB1, viB2 = vv.z + eB2;
        const float siA0 = qA.x - kv.x + eA0, siA1 = qA.y - kv.y + eA1, siA2 = qA.z - kv.z + eA2;
        const float siB0 = qB.x - kv.x + eB0, siB1 = qB.y - kv.y + eB1, siB2 = qB.z - kv.z + eB2;

        // attn-MLP in packed f16, both pairs (aw2/ab2 pre-scaled by L2E)
        const h2 sAx = pkrtz(siA0, siA0), sAy = pkrtz(siA1, siA1), sAz = pkrtz(siA2, siA2);
        const h2 sBx = pkrtz(siB0, siB0), sBy = pkrtz(siB1, siB1), sBz = pkrtz(siB2, siB2);
        float mA0 = mb_0, mA1 = mb_1, mA2 = mb_2;
        float mB0 = mb_0, mB1 = mb_1, mB2 = mb_2;
        #pragma unroll
        for (int gp = 0; gp < 6; ++gp) {
            const h2 b1p = uash2(wsp[114+gp]);
            const h2 u0 = uash2(wsp[96+0*6+gp]);
            const h2 u1 = uash2(wsp[96+1*6+gp]);
            const h2 u2 = uash2(wsp[96+2*6+gp]);
            const h2 v0 = uash2(wsp[120+gp*3+0]);
            const h2 v1 = uash2(wsp[120+gp*3+1]);
            const h2 v2 = uash2(wsp[120+gp*3+2]);
            h2 accA = b1p, accB = b1p;
            accA = __builtin_elementwise_fma(sAx, u0, accA);
            accA = __builtin_elementwise_fma(sAy, u1, accA);
            accA = __builtin_elementwise_fma(sAz, u2, accA);
            accB = __builtin_elementwise_fma(sBx, u0, accB);
            accB = __builtin_elementwise_fma(sBy, u1, accB);
            accB = __builtin_elementwise_fma(sBz, u2, accB);
            h2 hA = hmax2(accA, z2), hB = hmax2(accB, z2);
            mA0 = dot2acc(hA, v0, mA0);
            mA1 = dot2acc(hA, v1, mA1);
            mA2 = dot2acc(hA, v2, mA2);
            mB0 = dot2acc(hB, v0, mB0);
            mB1 = dot2acc(hB, v1, mB1);
            mB2 = dot2acc(hB, v2, mB2);
        }

        // softmax over j (DPP row sums; exponents already in log2 domain)
        const float pA0 = __builtin_amdgcn_exp2f(mA0);
        const float pA1 = __builtin_amdgcn_exp2f(mA1);
        const float pA2 = __builtin_amdgcn_exp2f(mA2);
        const float pB0 = __builtin_amdgcn_exp2f(mB0);
        const float pB1 = __builtin_amdgcn_exp2f(mB1);
        const float pB2 = __builtin_amdgcn_exp2f(mB2);

        const float nA0 = dpp_add16(pA0 * viA0);
        const float nA1 = dpp_add16(pA1 * viA1);
        const float nA2 = dpp_add16(pA2 * viA2);
        const float dA0 = dpp_add16(pA0);
        const float dA1 = dpp_add16(pA1);
        const float dA2 = dpp_add16(pA2);
        const float nB0 = dpp_add16(pB0 * viB0);
        const float nB1 = dpp_add16(pB1 * viB1);
        const float nB2 = dpp_add16(pB2 * viB2);
        const float dB0 = dpp_add16(pB0);
        const float dB1 = dpp_add16(pB1);
        const float dB2 = dpp_add16(pB2);

        if (j == 0) {
            s_sa[iA*3+0] = nA0 * __builtin_amdgcn_rcpf(dA0);
            s_sa[iA*3+1] = nA1 * __builtin_amdgcn_rcpf(dA1);
            s_sa[iA*3+2] = nA2 * __builtin_amdgcn_rcpf(dA2);
            s_sa[iB*3+0] = nB0 * __builtin_amdgcn_rcpf(dB0);
            s_sa[iB*3+1] = nB1 * __builtin_amdgcn_rcpf(dB1);
            s_sa[iB*3+2] = nB2 * __builtin_amdgcn_rcpf(dB2);
        }
    }
    __builtin_amdgcn_wave_barrier();   // s_sa writes before tail reads

    // ---- phase 3: MLP 48->48->48->1 (lanes 0..47) ----
    if (ln < 48) {
        const int o = ln;
        float a0 = 0.f, a1 = 0.f, a2 = 0.f, a3 = 0.f;
        #pragma unroll
        for (int c = 0; c < 48; c += 4) {
            const float4 sa = *(const float4*)&s_sa[c];   // broadcast read
            a0 = fmaf(sa.x, mw1[(c+0)*48+o], a0);
            a1 = fmaf(sa.y, mw1[(c+1)*48+o], a1);
            a2 = fmaf(sa.z, mw1[(c+2)*48+o], a2);
            a3 = fmaf(sa.w, mw1[(c+3)*48+o], a3);
        }
        s_h1[o] = fmaxf((a0+a1) + (a2+a3) + mb1[o], 0.0f);
        __builtin_amdgcn_wave_barrier();   // same-wave LDS handoff
        float b0 = 0.f, b1 = 0.f, b2 = 0.f, b3 = 0.f;
        #pragma unroll
        for (int c = 0; c < 48; c += 4) {
            const float4 hh = *(const float4*)&s_h1[c];
            b0 = fmaf(hh.x, mw2[(c+0)*48+o], b0);
            b1 = fmaf(hh.y, mw2[(c+1)*48+o], b1);
            b2 = fmaf(hh.z, mw2[(c+2)*48+o], b2);
            b3 = fmaf(hh.w, mw2[(c+3)*48+o], b3);
        }
        const float h2v = fmaxf((b0+b1) + (b2+b3) + mb2[o], 0.0f);
        const float fv = h2v * mw3[o];
        const float r = dpp_add16(fv);     // row sums in lanes 0,16,32
        const int ri = __builtin_bit_cast(int, r);
        const float tot =
            __builtin_bit_cast(float, __builtin_amdgcn_readlane(ri, 0)) +
            __builtin_bit_cast(float, __builtin_amdgcn_readlane(ri, 16)) +
            __builtin_bit_cast(float, __builtin_amdgcn_readlane(ri, 32));
        if (o == 0) out[g] = tot + mb3[0];
    }
}

extern "C" void kernel_launch(void* const* d_in, const int* in_sizes, int n_in,
                              void* d_out, int out_size, void* d_ws, size_t ws_size,
                              hipStream_t stream) {
    const float* data = (const float*)d_in[1];
    unsigned* ws = (unsigned*)d_ws;
    const int groups = out_size;  // B*G = 16384

    wpack<<<1, 256, 0, stream>>>(
        (const float*)d_in[5],   // pw2
        (const float*)d_in[7],   // aw1
        (const float*)d_in[8],   // ab1
        (const float*)d_in[9],   // aw2
        ws);

    pt_main<<<groups, 64, 0, stream>>>(
        data,
        (const float*)d_in[2],   // wqkv
        (const float*)d_in[3],   // pw1
        (const float*)d_in[4],   // pb1
        (const float*)d_in[6],   // pb2
        (const float*)d_in[10],  // ab2
        (const float*)d_in[11],  // mw1
        (const float*)d_in[12],  // mb1
        (const float*)d_in[13],  // mw2
        (const float*)d_in[14],  // mb2
        (const float*)d_in[15],  // mw3
        (const float*)d_in[16],  // mb3
        ws,
        (float*)d_out);
}

// Round 14
// 136.286 us; speedup vs baseline: 1.1141x; 1.0122x over previous
//
#include <hip/hip_runtime.h>

// Point-transformer block. R13 = R12 (one wave per block, wave-autonomous,
// zero __syncthreads, SGPR small-weights, L2E folded) + phase-3 MLP
// weights packed as f16 pairs in d_ws: 24 dword loads + 24 dot2 per layer
// (was 48 loads + 48 fma), and single data[] load shared by phases 1a/1b.

typedef _Float16 h2 __attribute__((ext_vector_type(2)));
typedef _Float16 h8 __attribute__((ext_vector_type(8)));

#define AH_STRIDE 36    // a-table row stride in dwords (32 data + 4 pad)
#define MW1_OFF  256    // ws offset: mw1 pairs, [24][48] dwords
#define MW2_OFF 1408    // ws offset: mw2 pairs, [24][48] dwords

union H8U { h8 v; h2 p[4]; unsigned u[4]; };

__device__ __forceinline__ h2 pkrtz(float a, float b) {
    return __builtin_bit_cast(h2, __builtin_amdgcn_cvt_pkrtz(a, b));
}
__device__ __forceinline__ h2 uash2(unsigned u) {
    return __builtin_bit_cast(h2, u);
}
__device__ __forceinline__ h2 hmax2(h2 a, h2 b) {
    return __builtin_elementwise_max(a, b);   // v_pk_max_f16
}

#if __has_builtin(__builtin_amdgcn_fdot2)
__device__ __forceinline__ float dot2acc(h2 a, h2 b, float c) {
    return __builtin_amdgcn_fdot2(a, b, c, false);
}
#else
__device__ __forceinline__ float dot2acc(h2 a, h2 b, float c) {
    float d;
    asm("v_dot2_f32_f16 %0, %1, %2, %3"
        : "=v"(d)
        : "v"(__builtin_bit_cast(int, a)), "v"(__builtin_bit_cast(int, b)), "v"(c));
    return d;
}
#endif

// sum across the 16-lane DPP row via row_ror 1,2,4,8 (all lanes get total)
__device__ __forceinline__ float dpp_add16(float x) {
    float s = x;
    int t;
    t = __builtin_amdgcn_update_dpp(0, __builtin_bit_cast(int, s), 0x121, 0xf, 0xf, false);
    s += __builtin_bit_cast(float, t);
    t = __builtin_amdgcn_update_dpp(0, __builtin_bit_cast(int, s), 0x122, 0xf, 0xf, false);
    s += __builtin_bit_cast(float, t);
    t = __builtin_amdgcn_update_dpp(0, __builtin_bit_cast(int, s), 0x124, 0xf, 0xf, false);
    s += __builtin_bit_cast(float, t);
    t = __builtin_amdgcn_update_dpp(0, __builtin_bit_cast(int, s), 0x128, 0xf, 0xf, false);
    s += __builtin_bit_cast(float, t);
    return s;
}

// ---- pre-kernel: pack f16-pair weight tables into workspace ----
// block 0, t<138: small tables (pw2 / aw1 / ab1 / aw2*L2E) as in R10.
// all blocks: mw1/mw2 as c-pair tables  ws[OFF + cp*48 + o] = (w[2cp][o], w[2cp+1][o])
__global__ void wpack(const float* __restrict__ pw2, const float* __restrict__ aw1,
                      const float* __restrict__ ab1, const float* __restrict__ aw2,
                      const float* __restrict__ mw1, const float* __restrict__ mw2,
                      unsigned* __restrict__ ws) {
    const int t = threadIdx.x;
    const float L2E = 1.44269504f;
    if (blockIdx.x == 0) {
        if (t < 96) {
            const int hp = t & 31, c = t >> 5;
            ws[c*32+hp] = __builtin_bit_cast(unsigned, pkrtz(pw2[(2*hp)*3+c], pw2[(2*hp+1)*3+c]));
        } else if (t < 114) {
            const int idx = t - 96, r = idx / 6, gp = idx % 6;
            ws[96+r*6+gp] = __builtin_bit_cast(unsigned, pkrtz(aw1[r*12+2*gp], aw1[r*12+2*gp+1]));
        } else if (t < 120) {
            const int gp = t - 114;
            ws[114+gp] = __builtin_bit_cast(unsigned, pkrtz(ab1[2*gp], ab1[2*gp+1]));
        } else if (t < 138) {
            const int idx = t - 120, gp = idx / 3, c = idx % 3;
            ws[120+gp*3+c] = __builtin_bit_cast(unsigned,
                pkrtz(aw2[(2*gp)*3+c] * L2E, aw2[(2*gp+1)*3+c] * L2E));
        }
    }
    // mw1/mw2 pair tables: 1152 entries each
    const int idx = blockIdx.x * 256 + t;
    if (idx < 1152) {
        const int cp = idx / 48, o = idx % 48;
        ws[MW1_OFF + idx] = __builtin_bit_cast(unsigned,
            pkrtz(mw1[(2*cp)*48+o], mw1[(2*cp+1)*48+o]));
        ws[MW2_OFF + idx] = __builtin_bit_cast(unsigned,
            pkrtz(mw2[(2*cp)*48+o], mw2[(2*cp+1)*48+o]));
    }
}

__global__ __launch_bounds__(64, 8) void pt_main(
    const float* __restrict__ data,     // (BG, 16, 3)
    const float* __restrict__ wqkv,     // (3, 9)
    const float* __restrict__ pw1,      // (3, 64)
    const float* __restrict__ pb1,      // (64)
    const float* __restrict__ pb2,      // (3)
    const float* __restrict__ ab2,      // (3)
    const float* __restrict__ mb1,      // (48)
    const float* __restrict__ mb2,      // (48)
    const float* __restrict__ mw3,      // (48, 1)
    const float* __restrict__ mb3,      // (1)
    const unsigned* __restrict__ wsp,   // packed f16-pair weights
    float* __restrict__ out)            // (BG)
{
    __shared__ __attribute__((aligned(16))) float s_q4[64], s_k4[64], s_v4[64];
    __shared__ __attribute__((aligned(16))) float s_sa[48];
    __shared__ __attribute__((aligned(16))) float s_h1[48];
    __shared__ __attribute__((aligned(16))) unsigned s_a1h[16 * AH_STRIDE];
    __shared__ __attribute__((aligned(16))) unsigned s_a2h[16 * AH_STRIDE];

    const int ln = threadIdx.x;
    const int g  = blockIdx.x;

    // single data[] load for both phase-1 stages (same point p for 1a & 1b)
    const int p  = ln & 15;
    const float x0 = data[g*48 + p*3 + 0];
    const float x1 = data[g*48 + p*3 + 1];
    const float x2 = data[g*48 + p*3 + 2];

    // ---- phase 1a: qkv (lanes 0..47), stride-4 layout ----
    if (ln < 48) {
        const int sec = ln >> 4;
        float* dst = (sec == 0) ? s_q4 : (sec == 1) ? s_k4 : s_v4;
        #pragma unroll
        for (int c = 0; c < 3; ++c) {
            dst[p*4+c] = fmaf(x0, wqkv[0*9 + sec*3 + c],
                         fmaf(x1, wqkv[1*9 + sec*3 + c],
                         x2 * wqkv[2*9 + sec*3 + c]));
        }
        dst[p*4+3] = 0.0f;
    }

    // ---- phase 1b: a-tables. lane -> point p, 16 hiddens at (ln>>4)*16 ----
    {
        const int qd = ln >> 4;
        const int hc = qd << 4;
        float s[16];
        #pragma unroll
        for (int c = 0; c < 16; ++c) {
            const int h = hc + c;
            s[c] = fmaf(x0, pw1[h], fmaf(x1, pw1[64+h], x2 * pw1[128+h]));
        }
        uint4 a1u0, a1u1, a2u0, a2u1;
        #pragma unroll
        for (int d = 0; d < 4; ++d) {
            const int c = d * 2;
            (&a1u0.x)[d] = __builtin_bit_cast(unsigned, pkrtz(s[c]   + pb1[hc+c],   s[c+1] + pb1[hc+c+1]));
            (&a1u1.x)[d] = __builtin_bit_cast(unsigned, pkrtz(s[8+c] + pb1[hc+8+c], s[9+c] + pb1[hc+9+c]));
            (&a2u0.x)[d] = __builtin_bit_cast(unsigned, pkrtz(s[c],   s[c+1]));
            (&a2u1.x)[d] = __builtin_bit_cast(unsigned, pkrtz(s[8+c], s[9+c]));
        }
        const int base = p * AH_STRIDE + (qd << 3);
        *(uint4*)&s_a1h[base]     = a1u0;
        *(uint4*)&s_a1h[base + 4] = a1u1;
        *(uint4*)&s_a2h[base]     = a2u0;
        *(uint4*)&s_a2h[base + 4] = a2u1;
    }
    __builtin_amdgcn_wave_barrier();   // order DS writes before phase-2 reads

    // ---- phase 2: 4 pairs per lane, processed 2+2. j=ln&15, i in {q,q+4,q+8,q+12} ----
    const int j = p, q = ln >> 4;
    const float4 kv = *(const float4*)&s_k4[j*4];
    const float4 vv = *(const float4*)&s_v4[j*4];
    const h2 z2 = {(_Float16)0, (_Float16)0};
    const float L2E = 1.44269504f;
    const float mb_0 = ab2[0] * L2E, mb_1 = ab2[1] * L2E, mb_2 = ab2[2] * L2E;

    // hoist the j-side a-table (shared by all 4 pairs): 8 x b128
    H8U ajr[8];
    #pragma unroll
    for (int cc = 0; cc < 8; ++cc)
        ajr[cc].v = *(const h8*)&s_a2h[j * AH_STRIDE + cc*4];

    #pragma unroll
    for (int half = 0; half < 2; ++half) {
        const int iA = q + 8*half, iB = iA + 4;

        float eA0 = pb2[0], eA1 = pb2[1], eA2 = pb2[2];
        float eB0 = pb2[0], eB1 = pb2[1], eB2 = pb2[2];
        #pragma unroll
        for (int cc = 0; cc < 8; ++cc) {
            H8U aiA, aiB;
            aiA.v = *(const h8*)&s_a1h[iA * AH_STRIDE + cc*4];
            aiB.v = *(const h8*)&s_a1h[iB * AH_STRIDE + cc*4];
            #pragma unroll
            for (int m = 0; m < 4; ++m) {
                const int hp = cc*4 + m;
                const h2 w0 = uash2(wsp[0*32+hp]);
                const h2 w1 = uash2(wsp[1*32+hp]);
                const h2 w2 = uash2(wsp[2*32+hp]);
                h2 rA = hmax2(aiA.p[m] - ajr[cc].p[m], z2);
                h2 rB = hmax2(aiB.p[m] - ajr[cc].p[m], z2);
                eA0 = dot2acc(rA, w0, eA0);
                eA1 = dot2acc(rA, w1, eA1);
                eA2 = dot2acc(rA, w2, eA2);
                eB0 = dot2acc(rB, w0, eB0);
                eB1 = dot2acc(rB, w1, eB1);
                eB2 = dot2acc(rB, w2, eB2);
            }
        }

        const float4 qA = *(const float4*)&s_q4[iA*4];
        const float4 qB = *(const float4*)&s_q4[iB*4];

        const float viA0 = vv.x + eA0, viA1 = vv.y + eA1, viA2 = vv.z + eA2;
        const float viB0 = vv.x + eB0, viB1 = vv.y + eB1, viB2 = vv.z + eB2;
        const float siA0 = qA.x - kv.x + eA0, siA1 = qA.y - kv.y + eA1, siA2 = qA.z - kv.z + eA2;
        const float siB0 = qB.x - kv.x + eB0, siB1 = qB.y - kv.y + eB1, siB2 = qB.z - kv.z + eB2;

        // attn-MLP in packed f16, both pairs (aw2/ab2 pre-scaled by L2E)
        const h2 sAx = pkrtz(siA0, siA0), sAy = pkrtz(siA1, siA1), sAz = pkrtz(siA2, siA2);
        const h2 sBx = pkrtz(siB0, siB0), sBy = pkrtz(siB1, siB1), sBz = pkrtz(siB2, siB2);
        float mA0 = mb_0, mA1 = mb_1, mA2 = mb_2;
        float mB0 = mb_0, mB1 = mb_1, mB2 = mb_2;
        #pragma unroll
        for (int gp = 0; gp < 6; ++gp) {
            const h2 b1p = uash2(wsp[114+gp]);
            const h2 u0 = uash2(wsp[96+0*6+gp]);
            const h2 u1 = uash2(wsp[96+1*6+gp]);
            const h2 u2 = uash2(wsp[96+2*6+gp]);
            const h2 v0 = uash2(wsp[120+gp*3+0]);
            const h2 v1 = uash2(wsp[120+gp*3+1]);
            const h2 v2 = uash2(wsp[120+gp*3+2]);
            h2 accA = b1p, accB = b1p;
            accA = __builtin_elementwise_fma(sAx, u0, accA);
            accA = __builtin_elementwise_fma(sAy, u1, accA);
            accA = __builtin_elementwise_fma(sAz, u2, accA);
            accB = __builtin_elementwise_fma(sBx, u0, accB);
            accB = __builtin_elementwise_fma(sBy, u1, accB);
            accB = __builtin_elementwise_fma(sBz, u2, accB);
            h2 hA = hmax2(accA, z2), hB = hmax2(accB, z2);
            mA0 = dot2acc(hA, v0, mA0);
            mA1 = dot2acc(hA, v1, mA1);
            mA2 = dot2acc(hA, v2, mA2);
            mB0 = dot2acc(hB, v0, mB0);
            mB1 = dot2acc(hB, v1, mB1);
            mB2 = dot2acc(hB, v2, mB2);
        }

        // softmax over j (DPP row sums; exponents already in log2 domain)
        const float pA0 = __builtin_amdgcn_exp2f(mA0);
        const float pA1 = __builtin_amdgcn_exp2f(mA1);
        const float pA2 = __builtin_amdgcn_exp2f(mA2);
        const float pB0 = __builtin_amdgcn_exp2f(mB0);
        const float pB1 = __builtin_amdgcn_exp2f(mB1);
        const float pB2 = __builtin_amdgcn_exp2f(mB2);

        const float nA0 = dpp_add16(pA0 * viA0);
        const float nA1 = dpp_add16(pA1 * viA1);
        const float nA2 = dpp_add16(pA2 * viA2);
        const float dA0 = dpp_add16(pA0);
        const float dA1 = dpp_add16(pA1);
        const float dA2 = dpp_add16(pA2);
        const float nB0 = dpp_add16(pB0 * viB0);
        const float nB1 = dpp_add16(pB1 * viB1);
        const float nB2 = dpp_add16(pB2 * viB2);
        const float dB0 = dpp_add16(pB0);
        const float dB1 = dpp_add16(pB1);
        const float dB2 = dpp_add16(pB2);

        if (j == 0) {
            s_sa[iA*3+0] = nA0 * __builtin_amdgcn_rcpf(dA0);
            s_sa[iA*3+1] = nA1 * __builtin_amdgcn_rcpf(dA1);
            s_sa[iA*3+2] = nA2 * __builtin_amdgcn_rcpf(dA2);
            s_sa[iB*3+0] = nB0 * __builtin_amdgcn_rcpf(dB0);
            s_sa[iB*3+1] = nB1 * __builtin_amdgcn_rcpf(dB1);
            s_sa[iB*3+2] = nB2 * __builtin_amdgcn_rcpf(dB2);
        }
    }
    __builtin_amdgcn_wave_barrier();   // s_sa writes before tail reads

    // ---- phase 3: MLP 48->48->48->1 (lanes 0..47), f16-pair weights ----
    if (ln < 48) {
        const int o = ln;
        float a0 = 0.f, a1 = 0.f;
        #pragma unroll
        for (int c = 0; c < 48; c += 4) {
            const float4 sa = *(const float4*)&s_sa[c];   // broadcast read
            const h2 pa = pkrtz(sa.x, sa.y);
            const h2 pb = pkrtz(sa.z, sa.w);
            a0 = dot2acc(pa, uash2(wsp[MW1_OFF + (c>>1)*48 + o]), a0);
            a1 = dot2acc(pb, uash2(wsp[MW1_OFF + ((c>>1)+1)*48 + o]), a1);
        }
        s_h1[o] = fmaxf(a0 + a1 + mb1[o], 0.0f);
        __builtin_amdgcn_wave_barrier();   // same-wave LDS handoff
        float b0 = 0.f, b1 = 0.f;
        #pragma unroll
        for (int c = 0; c < 48; c += 4) {
            const float4 hh = *(const float4*)&s_h1[c];
            const h2 pa = pkrtz(hh.x, hh.y);
            const h2 pb = pkrtz(hh.z, hh.w);
            b0 = dot2acc(pa, uash2(wsp[MW2_OFF + (c>>1)*48 + o]), b0);
            b1 = dot2acc(pb, uash2(wsp[MW2_OFF + ((c>>1)+1)*48 + o]), b1);
        }
        const float h2v = fmaxf(b0 + b1 + mb2[o], 0.0f);
        const float fv = h2v * mw3[o];
        const float r = dpp_add16(fv);     // row sums in lanes 0,16,32
        const int ri = __builtin_bit_cast(int, r);
        const float tot =
            __builtin_bit_cast(float, __builtin_amdgcn_readlane(ri, 0)) +
            __builtin_bit_cast(float, __builtin_amdgcn_readlane(ri, 16)) +
            __builtin_bit_cast(float, __builtin_amdgcn_readlane(ri, 32));
        if (o == 0) out[g] = tot + mb3[0];
    }
}

extern "C" void kernel_launch(void* const* d_in, const int* in_sizes, int n_in,
                              void* d_out, int out_size, void* d_ws, size_t ws_size,
                              hipStream_t stream) {
    const float* data = (const float*)d_in[1];
    unsigned* ws = (unsigned*)d_ws;
    const int groups = out_size;  // B*G = 16384

    wpack<<<5, 256, 0, stream>>>(
        (const float*)d_in[5],   // pw2
        (const float*)d_in[7],   // aw1
        (const float*)d_in[8],   // ab1
        (const float*)d_in[9],   // aw2
        (const float*)d_in[11],  // mw1
        (const float*)d_in[13],  // mw2
        ws);

    pt_main<<<groups, 64, 0, stream>>>(
        data,
        (const float*)d_in[2],   // wqkv
        (const float*)d_in[3],   // pw1
        (const float*)d_in[4],   // pb1
        (const float*)d_in[6],   // pb2
        (const float*)d_in[10],  // ab2
        (const float*)d_in[12],  // mb1
        (const float*)d_in[14],  // mb2
        (const float*)d_in[15],  // mw3
        (const float*)d_in[16],  // mb3
        ws,
        (float*)d_out);
}